// Round 1
// baseline (2002.297 us; speedup 1.0000x reference)
//
#include <hip/hip_runtime.h>
#include <cstddef>

// ---------------------------------------------------------------------------
// HGTConv, algebraically reduced:
//   softmax(scores).mean(-1) == 1/8 exactly  =>  attention path is dead code.
//   segment_sum is linear  =>
//     out = relu( mx @ (Wv@Wm@Wout)/8 + beta*((bv@Wm+bm)@Wout)/8 + bout + x )
//   with mx = segsum(x[src])/max(cnt,1), beta = (cnt>0).
// ---------------------------------------------------------------------------

#define DD 256

// C[256x256] = alpha * A @ B   (row-major). One block per output row.
__global__ __launch_bounds__(256) void gemm256(const float* __restrict__ A,
                                               const float* __restrict__ B,
                                               float* __restrict__ C, float alpha) {
    __shared__ float As[DD];
    const int r = blockIdx.x;
    const int c = threadIdx.x;
    As[c] = A[r * DD + c];
    __syncthreads();
    float acc = 0.f;
#pragma unroll 8
    for (int k = 0; k < DD; ++k) acc += As[k] * B[k * DD + c];
    C[r * DD + c] = alpha * acc;
}

// bbeta[c] = ((bv@Wm + bm) @ Wout)[c] / 8
__global__ __launch_bounds__(256) void bias_fuse(const float* __restrict__ bv,
                                                 const float* __restrict__ Wm,
                                                 const float* __restrict__ bm,
                                                 const float* __restrict__ Wout,
                                                 float* __restrict__ bbeta) {
    __shared__ float t[DD];
    const int c = threadIdx.x;
    float acc = bm[c];
#pragma unroll 8
    for (int k = 0; k < DD; ++k) acc += bv[k] * Wm[k * DD + c];
    t[c] = acc;
    __syncthreads();
    float acc2 = 0.f;
#pragma unroll 8
    for (int k = 0; k < DD; ++k) acc2 += t[k] * Wout[k * DD + c];
    bbeta[c] = acc2 * 0.125f;
}

// One wave (64 lanes) per edge: gather x[src] as float4/lane, atomicAdd into
// sx[dst]; lane 0 bumps the count.
__global__ __launch_bounds__(256) void edge_scatter(const float* __restrict__ xsrc,
                                                    const int* __restrict__ src,
                                                    const int* __restrict__ dst,
                                                    float* __restrict__ sx,
                                                    float* __restrict__ cnt, int nE) {
    const int e = blockIdx.x * 4 + (threadIdx.x >> 6);
    const int lane = threadIdx.x & 63;
    if (e >= nE) return;
    const int s = src[e];
    const int d = dst[e];
    const float4 v = ((const float4*)(xsrc + (size_t)s * DD))[lane];
    float* base = sx + (size_t)d * DD + lane * 4;
    atomicAdd(base + 0, v.x);
    atomicAdd(base + 1, v.y);
    atomicAdd(base + 2, v.z);
    atomicAdd(base + 3, v.w);
    if (lane == 0) atomicAdd(cnt + d, 1.0f);
}

// Finalize: out = relu( (sx/max(cnt,1)) @ Wf + beta*bb + bout + x ), in place
// over `base` (block owns 32 full rows -> in-place safe: all global reads of
// those rows happen before the epilogue stores).
#define BR 32
#define BK 32
__global__ __launch_bounds__(256) void finalize_gemm(float* __restrict__ base,
                                                     const float* __restrict__ x,
                                                     const float* __restrict__ Wf,
                                                     const float* __restrict__ bb,
                                                     const float* __restrict__ bout,
                                                     const float* __restrict__ cnt,
                                                     int M) {
    __shared__ float As[BK][36];   // transposed: As[k][r], pad keeps 16B align
    __shared__ float Bs[BK * DD];
    __shared__ float rs[BR], bt[BR];

    const int tid = threadIdx.x;
    const int r0 = blockIdx.x * BR;
    const int cx = tid & 63;   // column group: cols cx*4 .. cx*4+3
    const int ry = tid >> 6;   // row group:   rows ry*8 .. ry*8+7

    if (tid < BR) {
        const int r = r0 + tid;
        const float c = (r < M) ? cnt[r] : 0.f;
        rs[tid] = 1.0f / fmaxf(c, 1.0f);
        bt[tid] = (c > 0.f) ? 1.0f : 0.f;
    }

    float acc[8][4];
#pragma unroll
    for (int i = 0; i < 8; ++i)
#pragma unroll
        for (int j = 0; j < 4; ++j) acc[i][j] = 0.f;

    const int lrow = tid >> 3;        // 0..31
    const int lk = (tid & 7) * 4;     // 0,4,...,28

    for (int kb = 0; kb < DD; kb += BK) {
        // stage A tile (transposed into As[k][r])
        {
            int gr = r0 + lrow;
            if (gr >= M) gr = M - 1;
            const float4 a = *(const float4*)(base + (size_t)gr * DD + kb + lk);
            As[lk + 0][lrow] = a.x;
            As[lk + 1][lrow] = a.y;
            As[lk + 2][lrow] = a.z;
            As[lk + 3][lrow] = a.w;
        }
        // stage B tile (32 x 256)
#pragma unroll
        for (int j = 0; j < 8; ++j) {
            const int f = j * 1024 + tid * 4;
            *(float4*)&Bs[f] = *(const float4*)(Wf + kb * DD + f);
        }
        __syncthreads();
#pragma unroll
        for (int k = 0; k < BK; ++k) {
            const float4 b = *(const float4*)&Bs[k * DD + cx * 4];
            const float4 a0 = *(const float4*)&As[k][ry * 8];
            const float4 a1 = *(const float4*)&As[k][ry * 8 + 4];
            const float av[8] = {a0.x, a0.y, a0.z, a0.w, a1.x, a1.y, a1.z, a1.w};
            const float bv4[4] = {b.x, b.y, b.z, b.w};
#pragma unroll
            for (int i = 0; i < 8; ++i)
#pragma unroll
                for (int j = 0; j < 4; ++j) acc[i][j] += av[i] * bv4[j];
        }
        __syncthreads();
    }

    const float4 bbv = *(const float4*)(bb + cx * 4);
    const float4 bov = *(const float4*)(bout + cx * 4);
#pragma unroll
    for (int i = 0; i < 8; ++i) {
        const int lr = ry * 8 + i;
        const int r = r0 + lr;
        if (r < M) {
            const float rsv = rs[lr];
            const float btv = bt[lr];
            const float4 xv = *(const float4*)(x + (size_t)r * DD + cx * 4);
            float4 o;
            o.x = fmaxf(acc[i][0] * rsv + btv * bbv.x + bov.x + xv.x, 0.f);
            o.y = fmaxf(acc[i][1] * rsv + btv * bbv.y + bov.y + xv.y, 0.f);
            o.z = fmaxf(acc[i][2] * rsv + btv * bbv.z + bov.z + xv.z, 0.f);
            o.w = fmaxf(acc[i][3] * rsv + btv * bbv.w + bov.w + xv.w, 0.f);
            *(float4*)(base + (size_t)r * DD + cx * 4) = o;
        }
    }
}

extern "C" void kernel_launch(void* const* d_in, const int* in_sizes, int n_in,
                              void* d_out, int out_size, void* d_ws, size_t ws_size,
                              hipStream_t stream) {
    // ---- inputs (setup_inputs dict order) ----
    const float* x_user = (const float*)d_in[0];
    const float* x_game = (const float*)d_in[1];
    // user: Wk(2) bk(3) Wq(4) bq(5) Wv(6) bv(7) Wout(8) bout(9)
    const float* Wv_user = (const float*)d_in[6];
    const float* bv_user = (const float*)d_in[7];
    const float* Wout_user = (const float*)d_in[8];
    const float* bout_user = (const float*)d_in[9];
    // game: 10..17
    const float* Wv_game = (const float*)d_in[14];
    const float* bv_game = (const float*)d_in[15];
    const float* Wout_game = (const float*)d_in[16];
    const float* bout_game = (const float*)d_in[17];
    // played: Wa(18) ba(19) Wm(20) bm(21); rev: 22..25
    const float* Wm_played = (const float*)d_in[20];
    const float* bm_played = (const float*)d_in[21];
    const float* Wm_rev = (const float*)d_in[24];
    const float* bm_rev = (const float*)d_in[25];
    const int* ei_played_src = (const int*)d_in[26];
    const int* ei_played_dst = (const int*)d_in[27];
    const int* ei_rev_src = (const int*)d_in[28];
    const int* ei_rev_dst = (const int*)d_in[29];

    const int n_user = in_sizes[0] / DD;
    const int n_game = in_sizes[1] / DD;
    const int e_played = in_sizes[26];
    const int e_rev = in_sizes[28];

    float* out = (float*)d_out;              // also the sx scatter buffer
    float* sx_user = out;                    // rows [0, n_user)
    float* sx_game = out + (size_t)n_user * DD;  // rows [n_user, n_user+n_game)

    // ---- workspace layout (bytes) ----
    char* ws = (char*)d_ws;
    float* cnt_user = (float*)ws;                                  // n_user
    float* cnt_game = cnt_user + n_user;                           // n_game
    float* T = cnt_game + n_game;                                  // 65536
    float* Wf_played = T + DD * DD;                                // 65536
    float* Wf_rev = Wf_played + DD * DD;                           // 65536
    float* bb_played = Wf_rev + DD * DD;                           // 256
    float* bb_rev = bb_played + DD;                                // 256
    (void)ws_size; (void)n_in; (void)out_size;

    // ---- zero the scatter accumulators ----
    hipMemsetAsync(out, 0, (size_t)(n_user + n_game) * DD * sizeof(float), stream);
    hipMemsetAsync(cnt_user, 0, (size_t)(n_user + n_game) * sizeof(float), stream);

    // ---- fused weights: Wf = Wv @ Wm @ Wout / 8 ----
    gemm256<<<DD, DD, 0, stream>>>(Wv_user, Wm_played, T, 1.0f);
    gemm256<<<DD, DD, 0, stream>>>(T, Wout_game, Wf_played, 0.125f);
    gemm256<<<DD, DD, 0, stream>>>(Wv_game, Wm_rev, T, 1.0f);
    gemm256<<<DD, DD, 0, stream>>>(T, Wout_user, Wf_rev, 0.125f);
    bias_fuse<<<1, DD, 0, stream>>>(bv_user, Wm_played, bm_played, Wout_game, bb_played);
    bias_fuse<<<1, DD, 0, stream>>>(bv_game, Wm_rev, bm_rev, Wout_user, bb_rev);

    // ---- edge scatter (raw x features + counts) ----
    edge_scatter<<<(e_played + 3) / 4, 256, 0, stream>>>(
        x_user, ei_played_src, ei_played_dst, sx_game, cnt_game, e_played);
    edge_scatter<<<(e_rev + 3) / 4, 256, 0, stream>>>(
        x_game, ei_rev_src, ei_rev_dst, sx_user, cnt_user, e_rev);

    // ---- finalize: normalize + fused GEMM + bias + residual + relu ----
    finalize_gemm<<<(n_user + BR - 1) / BR, 256, 0, stream>>>(
        sx_user, x_user, Wf_rev, bb_rev, bout_user, cnt_user, n_user);
    finalize_gemm<<<(n_game + BR - 1) / BR, 256, 0, stream>>>(
        sx_game, x_game, Wf_played, bb_played, bout_game, cnt_game, n_game);
}

// Round 2
// 753.993 us; speedup vs baseline: 2.6556x; 2.6556x over previous
//
#include <hip/hip_runtime.h>
#include <cstddef>

// ---------------------------------------------------------------------------
// HGTConv, algebraically reduced:
//   softmax(scores).mean(-1) == 1/8 exactly  =>  attention path is dead code.
//   segment_sum is linear  =>
//     out = relu( mx @ (Wv@Wm@Wout)/8 + beta*((bv@Wm+bm)@Wout)/8 + bout + x )
//   with mx = segsum(x[src])/max(cnt,1), beta = (cnt>0).
//
// R1: scatter-atomics (683us/dir, 806MB HBM write from L2 atomic thrash)
// replaced by CSR build (hist + scan + permute) + per-node gather-reduce.
// ---------------------------------------------------------------------------

#define DD 256

// ---- weight fusion ----------------------------------------------------------
// Two independent 256x256x256 GEMMs in one launch (blockIdx >> 8 selects).
__global__ __launch_bounds__(256) void gemm256x2(const float* __restrict__ A0,
                                                 const float* __restrict__ B0,
                                                 float* __restrict__ C0,
                                                 const float* __restrict__ A1,
                                                 const float* __restrict__ B1,
                                                 float* __restrict__ C1, float alpha) {
    __shared__ float As[DD];
    const int which = blockIdx.x >> 8;
    const int r = blockIdx.x & 255;
    const int c = threadIdx.x;
    const float* A = which ? A1 : A0;
    const float* B = which ? B1 : B0;
    float* C = which ? C1 : C0;
    As[c] = A[r * DD + c];
    __syncthreads();
    float acc = 0.f;
#pragma unroll 8
    for (int k = 0; k < DD; ++k) acc += As[k] * B[k * DD + c];
    C[r * DD + c] = alpha * acc;
}

// bbeta[c] = ((bv@Wm + bm) @ Wout)[c] / 8  — two edge types, blockIdx selects.
__global__ __launch_bounds__(256) void bias_fuse2(const float* __restrict__ bv0,
                                                  const float* __restrict__ Wm0,
                                                  const float* __restrict__ bm0,
                                                  const float* __restrict__ Wout0,
                                                  float* __restrict__ bb0,
                                                  const float* __restrict__ bv1,
                                                  const float* __restrict__ Wm1,
                                                  const float* __restrict__ bm1,
                                                  const float* __restrict__ Wout1,
                                                  float* __restrict__ bb1) {
    __shared__ float t[DD];
    const int w = blockIdx.x;
    const float* bv = w ? bv1 : bv0;
    const float* Wm = w ? Wm1 : Wm0;
    const float* bm = w ? bm1 : bm0;
    const float* Wout = w ? Wout1 : Wout0;
    float* bb = w ? bb1 : bb0;
    const int c = threadIdx.x;
    float acc = bm[c];
#pragma unroll 8
    for (int k = 0; k < DD; ++k) acc += bv[k] * Wm[k * DD + c];
    t[c] = acc;
    __syncthreads();
    float acc2 = 0.f;
#pragma unroll 8
    for (int k = 0; k < DD; ++k) acc2 += t[k] * Wout[k * DD + c];
    bb[c] = acc2 * 0.125f;
}

// ---- CSR build --------------------------------------------------------------
__global__ __launch_bounds__(256) void hist_kernel(const int* __restrict__ dst,
                                                   int* __restrict__ cnt, int E) {
    const int i = blockIdx.x * 256 + threadIdx.x;
    if (i < E) atomicAdd(&cnt[dst[i]], 1);
}

#define SCAN_CHUNK 2048
// In-place exclusive scan, stage 1: per-2048-chunk scan + chunk totals.
__global__ __launch_bounds__(256) void scan_chunk(int* __restrict__ off,
                                                  int* __restrict__ sums, int n) {
    __shared__ int ls[256];
    const int tid = threadIdx.x;
    const int base = blockIdx.x * SCAN_CHUNK + tid * 8;
    int v[8];
    int s = 0;
#pragma unroll
    for (int i = 0; i < 8; ++i) {
        const int idx = base + i;
        v[i] = (idx < n) ? off[idx] : 0;
        s += v[i];
    }
    ls[tid] = s;
    __syncthreads();
    for (int d = 1; d < 256; d <<= 1) {
        const int t = (tid >= d) ? ls[tid - d] : 0;
        __syncthreads();
        ls[tid] += t;
        __syncthreads();
    }
    int excl = tid ? ls[tid - 1] : 0;
    if (tid == 255) sums[blockIdx.x] = ls[255];
#pragma unroll
    for (int i = 0; i < 8; ++i) {
        const int idx = base + i;
        if (idx < n) off[idx] = excl;
        excl += v[i];
    }
}

// stage 2: exclusive-scan the (<=256) chunk totals in place.
__global__ __launch_bounds__(256) void scan_sums(int* __restrict__ sums, int nchunks) {
    __shared__ int ls[256];
    const int tid = threadIdx.x;
    ls[tid] = (tid < nchunks) ? sums[tid] : 0;
    __syncthreads();
    for (int d = 1; d < 256; d <<= 1) {
        const int t = (tid >= d) ? ls[tid - d] : 0;
        __syncthreads();
        ls[tid] += t;
        __syncthreads();
    }
    if (tid < nchunks) sums[tid] = tid ? ls[tid - 1] : 0;
}

// stage 3: add chunk offsets; off[n] = E.
__global__ __launch_bounds__(256) void scan_add(int* __restrict__ off,
                                                const int* __restrict__ sums,
                                                int n, int E) {
    const int idx = blockIdx.x * 256 + threadIdx.x;
    if (idx < n) off[idx] += sums[idx / SCAN_CHUNK];
    if (idx == n) off[n] = E;
}

// perm[pos] = src id, bucketed by dst via cursor (= copy of off).
__global__ __launch_bounds__(256) void permute_kernel(const int* __restrict__ src,
                                                      const int* __restrict__ dst,
                                                      int* __restrict__ cursor,
                                                      int* __restrict__ perm, int E) {
    const int i = blockIdx.x * 256 + threadIdx.x;
    if (i < E) {
        const int pos = atomicAdd(&cursor[dst[i]], 1);
        perm[pos] = src[i];
    }
}

// ---- gather-reduce: sx[d] = sum over edges of x[src]; one wave per dst ------
__global__ __launch_bounds__(256) void aggregate(const float* __restrict__ x,
                                                 const int* __restrict__ perm,
                                                 const int* __restrict__ off,
                                                 float* __restrict__ sx, int n) {
    const int d = blockIdx.x * 4 + (threadIdx.x >> 6);
    const int lane = threadIdx.x & 63;
    if (d >= n) return;
    const int e0 = off[d];
    const int e1 = off[d + 1];
    float4 acc = {0.f, 0.f, 0.f, 0.f};
    for (int e = e0; e < e1; ++e) {
        const int s = perm[e];
        const float4 v = ((const float4*)(x + (size_t)s * DD))[lane];
        acc.x += v.x;
        acc.y += v.y;
        acc.z += v.z;
        acc.w += v.w;
    }
    ((float4*)(sx + (size_t)d * DD))[lane] = acc;
}

// ---- finalize: out = relu((sx/max(cnt,1)) @ Wf + beta*bb + bout + x) --------
#define BR 32
#define BK 32
__global__ __launch_bounds__(256) void finalize_gemm(float* __restrict__ base,
                                                     const float* __restrict__ x,
                                                     const float* __restrict__ Wf,
                                                     const float* __restrict__ bb,
                                                     const float* __restrict__ bout,
                                                     const int* __restrict__ off,
                                                     int M) {
    __shared__ float As[BK][36];
    __shared__ float Bs[BK * DD];
    __shared__ float rs[BR], bt[BR];

    const int tid = threadIdx.x;
    const int r0 = blockIdx.x * BR;
    const int cx = tid & 63;
    const int ry = tid >> 6;

    if (tid < BR) {
        const int r = r0 + tid;
        const float c = (r < M) ? (float)(off[r + 1] - off[r]) : 0.f;
        rs[tid] = 1.0f / fmaxf(c, 1.0f);
        bt[tid] = (c > 0.f) ? 1.0f : 0.f;
    }

    float acc[8][4];
#pragma unroll
    for (int i = 0; i < 8; ++i)
#pragma unroll
        for (int j = 0; j < 4; ++j) acc[i][j] = 0.f;

    const int lrow = tid >> 3;
    const int lk = (tid & 7) * 4;

    for (int kb = 0; kb < DD; kb += BK) {
        {
            int gr = r0 + lrow;
            if (gr >= M) gr = M - 1;
            const float4 a = *(const float4*)(base + (size_t)gr * DD + kb + lk);
            As[lk + 0][lrow] = a.x;
            As[lk + 1][lrow] = a.y;
            As[lk + 2][lrow] = a.z;
            As[lk + 3][lrow] = a.w;
        }
#pragma unroll
        for (int j = 0; j < 8; ++j) {
            const int f = j * 1024 + tid * 4;
            *(float4*)&Bs[f] = *(const float4*)(Wf + kb * DD + f);
        }
        __syncthreads();
#pragma unroll
        for (int k = 0; k < BK; ++k) {
            const float4 b = *(const float4*)&Bs[k * DD + cx * 4];
            const float4 a0 = *(const float4*)&As[k][ry * 8];
            const float4 a1 = *(const float4*)&As[k][ry * 8 + 4];
            const float av[8] = {a0.x, a0.y, a0.z, a0.w, a1.x, a1.y, a1.z, a1.w};
            const float bv4[4] = {b.x, b.y, b.z, b.w};
#pragma unroll
            for (int i = 0; i < 8; ++i)
#pragma unroll
                for (int j = 0; j < 4; ++j) acc[i][j] += av[i] * bv4[j];
        }
        __syncthreads();
    }

    const float4 bbv = *(const float4*)(bb + cx * 4);
    const float4 bov = *(const float4*)(bout + cx * 4);
#pragma unroll
    for (int i = 0; i < 8; ++i) {
        const int lr = ry * 8 + i;
        const int r = r0 + lr;
        if (r < M) {
            const float rsv = rs[lr];
            const float btv = bt[lr];
            const float4 xv = *(const float4*)(x + (size_t)r * DD + cx * 4);
            float4 o;
            o.x = fmaxf(acc[i][0] * rsv + btv * bbv.x + bov.x + xv.x, 0.f);
            o.y = fmaxf(acc[i][1] * rsv + btv * bbv.y + bov.y + xv.y, 0.f);
            o.z = fmaxf(acc[i][2] * rsv + btv * bbv.z + bov.z + xv.z, 0.f);
            o.w = fmaxf(acc[i][3] * rsv + btv * bbv.w + bov.w + xv.w, 0.f);
            *(float4*)(base + (size_t)r * DD + cx * 4) = o;
        }
    }
}

extern "C" void kernel_launch(void* const* d_in, const int* in_sizes, int n_in,
                              void* d_out, int out_size, void* d_ws, size_t ws_size,
                              hipStream_t stream) {
    const float* x_user = (const float*)d_in[0];
    const float* x_game = (const float*)d_in[1];
    const float* Wv_user = (const float*)d_in[6];
    const float* bv_user = (const float*)d_in[7];
    const float* Wout_user = (const float*)d_in[8];
    const float* bout_user = (const float*)d_in[9];
    const float* Wv_game = (const float*)d_in[14];
    const float* bv_game = (const float*)d_in[15];
    const float* Wout_game = (const float*)d_in[16];
    const float* bout_game = (const float*)d_in[17];
    const float* Wm_played = (const float*)d_in[20];
    const float* bm_played = (const float*)d_in[21];
    const float* Wm_rev = (const float*)d_in[24];
    const float* bm_rev = (const float*)d_in[25];
    const int* ei_played_src = (const int*)d_in[26];
    const int* ei_played_dst = (const int*)d_in[27];
    const int* ei_rev_src = (const int*)d_in[28];
    const int* ei_rev_dst = (const int*)d_in[29];

    const int n_user = in_sizes[0] / DD;
    const int n_game = in_sizes[1] / DD;
    const int e_played = in_sizes[26];
    const int e_rev = in_sizes[28];

    float* out = (float*)d_out;
    float* sx_user = out;
    float* sx_game = out + (size_t)n_user * DD;

    // ---- workspace layout (floats first for 16B alignment) ----
    float* fws = (float*)d_ws;
    float* T0 = fws;                      // 65536
    float* T1 = T0 + DD * DD;             // 65536
    float* Wf_played = T1 + DD * DD;      // 65536
    float* Wf_rev = Wf_played + DD * DD;  // 65536
    float* bb_played = Wf_rev + DD * DD;  // 256
    float* bb_rev = bb_played + DD;       // 256
    int* iws = (int*)(bb_rev + DD);
    int* off_game = iws;                      // n_game+1
    int* off_user = off_game + (n_game + 1);  // n_user+1
    int* cursor_game = off_user + (n_user + 1);
    int* cursor_user = cursor_game + n_game;
    int* sums_game = cursor_user + n_user;  // 256
    int* sums_user = sums_game + 256;       // 256
    int* perm_played = sums_user + 256;     // E
    int* perm_rev = perm_played + e_played; // E
    (void)ws_size; (void)n_in; (void)out_size;

    // ---- zero histograms (off_game & off_user are contiguous) ----
    hipMemsetAsync(off_game, 0, (size_t)(n_game + n_user + 2) * sizeof(int), stream);

    // ---- weight fusion (independent of edge pipeline) ----
    gemm256x2<<<512, DD, 0, stream>>>(Wv_user, Wm_played, T0, Wv_game, Wm_rev, T1, 1.0f);
    gemm256x2<<<512, DD, 0, stream>>>(T0, Wout_game, Wf_played, T1, Wout_user, Wf_rev, 0.125f);
    bias_fuse2<<<2, DD, 0, stream>>>(bv_user, Wm_played, bm_played, Wout_game, bb_played,
                                     bv_game, Wm_rev, bm_rev, Wout_user, bb_rev);

    // ---- CSR build: played (dst = game) ----
    const int nch_g = (n_game + SCAN_CHUNK - 1) / SCAN_CHUNK;
    const int nch_u = (n_user + SCAN_CHUNK - 1) / SCAN_CHUNK;
    hist_kernel<<<(e_played + 255) / 256, 256, 0, stream>>>(ei_played_dst, off_game, e_played);
    hist_kernel<<<(e_rev + 255) / 256, 256, 0, stream>>>(ei_rev_dst, off_user, e_rev);
    scan_chunk<<<nch_g, 256, 0, stream>>>(off_game, sums_game, n_game);
    scan_chunk<<<nch_u, 256, 0, stream>>>(off_user, sums_user, n_user);
    scan_sums<<<1, 256, 0, stream>>>(sums_game, nch_g);
    scan_sums<<<1, 256, 0, stream>>>(sums_user, nch_u);
    scan_add<<<(n_game + 256) / 256, 256, 0, stream>>>(off_game, sums_game, n_game, e_played);
    scan_add<<<(n_user + 256) / 256, 256, 0, stream>>>(off_user, sums_user, n_user, e_rev);
    hipMemcpyAsync(cursor_game, off_game, (size_t)n_game * sizeof(int),
                   hipMemcpyDeviceToDevice, stream);
    hipMemcpyAsync(cursor_user, off_user, (size_t)n_user * sizeof(int),
                   hipMemcpyDeviceToDevice, stream);
    permute_kernel<<<(e_played + 255) / 256, 256, 0, stream>>>(
        ei_played_src, ei_played_dst, cursor_game, perm_played, e_played);
    permute_kernel<<<(e_rev + 255) / 256, 256, 0, stream>>>(
        ei_rev_src, ei_rev_dst, cursor_user, perm_rev, e_rev);

    // ---- gather-reduce (writes every row; no output memset needed) ----
    aggregate<<<(n_game + 3) / 4, 256, 0, stream>>>(x_user, perm_played, off_game,
                                                    sx_game, n_game);
    aggregate<<<(n_user + 3) / 4, 256, 0, stream>>>(x_game, perm_rev, off_user,
                                                    sx_user, n_user);

    // ---- finalize ----
    finalize_gemm<<<(n_user + BR - 1) / BR, 256, 0, stream>>>(
        sx_user, x_user, Wf_rev, bb_rev, bout_user, off_user, n_user);
    finalize_gemm<<<(n_game + BR - 1) / BR, 256, 0, stream>>>(
        sx_game, x_game, Wf_played, bb_played, bout_game, off_game, n_game);
}

// Round 3
// 628.725 us; speedup vs baseline: 3.1847x; 1.1992x over previous
//
#include <hip/hip_runtime.h>
#include <cstddef>

// ---------------------------------------------------------------------------
// HGTConv, algebraically reduced:
//   softmax(scores).mean(-1) == 1/8 exactly  =>  attention path is dead code.
//   segment_sum is linear  =>
//     out = relu( mx @ (Wv@Wm@Wout)/8 + beta*((bv@Wm+bm)@Wout)/8 + bout + x )
//   with mx = segsum(x[src])/max(cnt,1), beta = (cnt>0).
//
// R1: scatter-atomics -> CSR build + gather-reduce.
// R2: fuse aggregate+finalize into one kernel (kills 300MB sx round-trip);
//     GEMM on bf16 MFMA (16x16x32) with pre-swizzled bf16 B fragments.
// ---------------------------------------------------------------------------

#define DD 256

typedef __attribute__((ext_vector_type(8))) short short8;
typedef __attribute__((ext_vector_type(4))) float floatx4;

__device__ __forceinline__ short f2bf(float f) {
    union { float f; unsigned u; } c;
    c.f = f;
    unsigned r = c.u + 0x7fffu + ((c.u >> 16) & 1u);
    return (short)(r >> 16);
}

// ---- weight fusion ----------------------------------------------------------
// Two independent 256x256x256 fp32 GEMMs in one launch (T = Wv@Wm).
__global__ __launch_bounds__(256) void gemm256x2(const float* __restrict__ A0,
                                                 const float* __restrict__ B0,
                                                 float* __restrict__ C0,
                                                 const float* __restrict__ A1,
                                                 const float* __restrict__ B1,
                                                 float* __restrict__ C1) {
    __shared__ float As[DD];
    const int which = blockIdx.x >> 8;
    const int r = blockIdx.x & 255;
    const int c = threadIdx.x;
    const float* A = which ? A1 : A0;
    const float* B = which ? B1 : B0;
    float* C = which ? C1 : C0;
    As[c] = A[r * DD + c];
    __syncthreads();
    float acc = 0.f;
#pragma unroll 8
    for (int k = 0; k < DD; ++k) acc += As[k] * B[k * DD + c];
    C[r * DD + c] = acc;
}

// Wf = T@Wout * 0.125, emitted directly as bf16 in MFMA B-fragment order:
//   Bsw[((k>>5)*16 + (n>>4))*64 + ((n&15)|(((k>>3)&3)<<4))][k&7]
// so a lane's B-frag is one coalesced 16B load.
__global__ __launch_bounds__(256) void gemm256_swz_x2(const float* __restrict__ A0,
                                                      const float* __restrict__ B0,
                                                      short* __restrict__ C0,
                                                      const float* __restrict__ A1,
                                                      const float* __restrict__ B1,
                                                      short* __restrict__ C1) {
    __shared__ float As[DD];
    const int which = blockIdx.x >> 8;
    const int r = blockIdx.x & 255;  // k index of Wf
    const int c = threadIdx.x;       // n index of Wf
    const float* A = which ? A1 : A0;
    const float* B = which ? B1 : B0;
    short* C = which ? C1 : C0;
    As[c] = A[r * DD + c];
    __syncthreads();
    float acc = 0.f;
#pragma unroll 8
    for (int k = 0; k < DD; ++k) acc += As[k] * B[k * DD + c];
    const int idx = ((((r >> 5) * 16 + (c >> 4)) * 64 +
                      ((c & 15) | (((r >> 3) & 3) << 4))) << 3) + (r & 7);
    C[idx] = f2bf(acc * 0.125f);
}

// bbeta[c] = ((bv@Wm + bm) @ Wout)[c] / 8  — two edge types, blockIdx selects.
__global__ __launch_bounds__(256) void bias_fuse2(const float* __restrict__ bv0,
                                                  const float* __restrict__ Wm0,
                                                  const float* __restrict__ bm0,
                                                  const float* __restrict__ Wout0,
                                                  float* __restrict__ bb0,
                                                  const float* __restrict__ bv1,
                                                  const float* __restrict__ Wm1,
                                                  const float* __restrict__ bm1,
                                                  const float* __restrict__ Wout1,
                                                  float* __restrict__ bb1) {
    __shared__ float t[DD];
    const int w = blockIdx.x;
    const float* bv = w ? bv1 : bv0;
    const float* Wm = w ? Wm1 : Wm0;
    const float* bm = w ? bm1 : bm0;
    const float* Wout = w ? Wout1 : Wout0;
    float* bb = w ? bb1 : bb0;
    const int c = threadIdx.x;
    float acc = bm[c];
#pragma unroll 8
    for (int k = 0; k < DD; ++k) acc += bv[k] * Wm[k * DD + c];
    t[c] = acc;
    __syncthreads();
    float acc2 = 0.f;
#pragma unroll 8
    for (int k = 0; k < DD; ++k) acc2 += t[k] * Wout[k * DD + c];
    bb[c] = acc2 * 0.125f;
}

// ---- CSR build --------------------------------------------------------------
__global__ __launch_bounds__(256) void hist_kernel(const int* __restrict__ dst,
                                                   int* __restrict__ cnt, int E) {
    const int i = blockIdx.x * 256 + threadIdx.x;
    if (i < E) atomicAdd(&cnt[dst[i]], 1);
}

#define SCAN_CHUNK 2048
__global__ __launch_bounds__(256) void scan_chunk(int* __restrict__ off,
                                                  int* __restrict__ sums, int n) {
    __shared__ int ls[256];
    const int tid = threadIdx.x;
    const int base = blockIdx.x * SCAN_CHUNK + tid * 8;
    int v[8];
    int s = 0;
#pragma unroll
    for (int i = 0; i < 8; ++i) {
        const int idx = base + i;
        v[i] = (idx < n) ? off[idx] : 0;
        s += v[i];
    }
    ls[tid] = s;
    __syncthreads();
    for (int d = 1; d < 256; d <<= 1) {
        const int t = (tid >= d) ? ls[tid - d] : 0;
        __syncthreads();
        ls[tid] += t;
        __syncthreads();
    }
    int excl = tid ? ls[tid - 1] : 0;
    if (tid == 255) sums[blockIdx.x] = ls[255];
#pragma unroll
    for (int i = 0; i < 8; ++i) {
        const int idx = base + i;
        if (idx < n) off[idx] = excl;
        excl += v[i];
    }
}

__global__ __launch_bounds__(256) void scan_sums(int* __restrict__ sums, int nchunks) {
    __shared__ int ls[256];
    const int tid = threadIdx.x;
    ls[tid] = (tid < nchunks) ? sums[tid] : 0;
    __syncthreads();
    for (int d = 1; d < 256; d <<= 1) {
        const int t = (tid >= d) ? ls[tid - d] : 0;
        __syncthreads();
        ls[tid] += t;
        __syncthreads();
    }
    if (tid < nchunks) sums[tid] = tid ? ls[tid - 1] : 0;
}

__global__ __launch_bounds__(256) void scan_add(int* __restrict__ off,
                                                const int* __restrict__ sums,
                                                int n, int E) {
    const int idx = blockIdx.x * 256 + threadIdx.x;
    if (idx < n) off[idx] += sums[idx / SCAN_CHUNK];
    if (idx == n) off[n] = E;
}

__global__ __launch_bounds__(256) void permute_kernel(const int* __restrict__ src,
                                                      const int* __restrict__ dst,
                                                      int* __restrict__ cursor,
                                                      int* __restrict__ perm, int E) {
    const int i = blockIdx.x * 256 + threadIdx.x;
    if (i < E) {
        const int pos = atomicAdd(&cursor[dst[i]], 1);
        perm[pos] = src[i];
    }
}

// ---- fused aggregate + bf16-MFMA GEMM + epilogue ----------------------------
// Block = 64 dst rows, 256 threads (4 waves).
// Phase 1: each wave gathers/averages 16 rows from CSR -> bf16 A tile in LDS.
// Phase 2: wave w computes rows[0:64) x cols[w*64, w*64+64) with
//          v_mfma_f32_16x16x32_bf16; B frags are coalesced 16B global loads
//          from the pre-swizzled Wf (128KB, L2-resident).
// Epilogue: + beta*bb + bout + x, relu, store.
__global__ __launch_bounds__(256) void agg_gemm(const float* __restrict__ x_src,
                                                const float* __restrict__ x_res,
                                                const int* __restrict__ perm,
                                                const int* __restrict__ off,
                                                const short* __restrict__ Bsw,
                                                const float* __restrict__ bb,
                                                const float* __restrict__ bout,
                                                float* __restrict__ outp, int M) {
    __shared__ short As[64][264];  // +8 pad: ds_read_b128 A-frags 2-way (free)
    __shared__ float bt[64];

    const int tid = threadIdx.x;
    const int wave = tid >> 6;
    const int lane = tid & 63;
    const int r0 = blockIdx.x * 64;

    // ---- phase 1: aggregate 16 rows per wave ----
    for (int i = 0; i < 16; ++i) {
        const int lr = wave * 16 + i;
        const int r = r0 + lr;
        float4 acc = {0.f, 0.f, 0.f, 0.f};
        int deg = 0;
        if (r < M) {
            const int e0 = off[r];
            const int e1 = off[r + 1];
            deg = e1 - e0;
            for (int e = e0; e < e1; ++e) {
                const int s = perm[e];
                const float4 v = ((const float4*)(x_src + (size_t)s * DD))[lane];
                acc.x += v.x; acc.y += v.y; acc.z += v.z; acc.w += v.w;
            }
        }
        const float inv = 1.0f / fmaxf((float)deg, 1.0f);
        short4 b4;
        b4.x = f2bf(acc.x * inv);
        b4.y = f2bf(acc.y * inv);
        b4.z = f2bf(acc.z * inv);
        b4.w = f2bf(acc.w * inv);
        *(short4*)&As[lr][lane * 4] = b4;
        if (lane == 0) bt[lr] = (deg > 0) ? 1.0f : 0.0f;
    }
    __syncthreads();

    // ---- phase 2: MFMA ----
    const int quad = lane >> 4;
    const int l16 = lane & 15;
    floatx4 acc[4][4];
#pragma unroll
    for (int rt = 0; rt < 4; ++rt)
#pragma unroll
        for (int ct = 0; ct < 4; ++ct) acc[rt][ct] = (floatx4){0.f, 0.f, 0.f, 0.f};

    for (int kb8 = 0; kb8 < 8; ++kb8) {
        short8 af[4];
#pragma unroll
        for (int rt = 0; rt < 4; ++rt)
            af[rt] = *(const short8*)&As[rt * 16 + l16][kb8 * 32 + quad * 8];
        short8 bf[4];
        const short* bp = Bsw + (((size_t)(kb8 * 16 + wave * 4) * 64 + lane) << 3);
#pragma unroll
        for (int ct = 0; ct < 4; ++ct)
            bf[ct] = *(const short8*)(bp + (ct << 9));
#pragma unroll
        for (int rt = 0; rt < 4; ++rt)
#pragma unroll
            for (int ct = 0; ct < 4; ++ct)
                acc[rt][ct] = __builtin_amdgcn_mfma_f32_16x16x32_bf16(
                    af[rt], bf[ct], acc[rt][ct], 0, 0, 0);
    }

    // ---- epilogue ----
    float bbv[4], bov[4];
#pragma unroll
    for (int ct = 0; ct < 4; ++ct) {
        const int n = wave * 64 + ct * 16 + l16;
        bbv[ct] = bb[n];
        bov[ct] = bout[n];
    }
#pragma unroll
    for (int rt = 0; rt < 4; ++rt) {
#pragma unroll
        for (int j = 0; j < 4; ++j) {
            const int lr = rt * 16 + quad * 4 + j;
            const int r = r0 + lr;
            if (r < M) {
                const float btv = bt[lr];
                const float* xr = x_res + (size_t)r * DD;
                float* orow = outp + (size_t)r * DD;
#pragma unroll
                for (int ct = 0; ct < 4; ++ct) {
                    const int n = wave * 64 + ct * 16 + l16;
                    const float o = acc[rt][ct][j] + btv * bbv[ct] + bov[ct] + xr[n];
                    orow[n] = fmaxf(o, 0.f);
                }
            }
        }
    }
}

extern "C" void kernel_launch(void* const* d_in, const int* in_sizes, int n_in,
                              void* d_out, int out_size, void* d_ws, size_t ws_size,
                              hipStream_t stream) {
    const float* x_user = (const float*)d_in[0];
    const float* x_game = (const float*)d_in[1];
    const float* Wv_user = (const float*)d_in[6];
    const float* bv_user = (const float*)d_in[7];
    const float* Wout_user = (const float*)d_in[8];
    const float* bout_user = (const float*)d_in[9];
    const float* Wv_game = (const float*)d_in[14];
    const float* bv_game = (const float*)d_in[15];
    const float* Wout_game = (const float*)d_in[16];
    const float* bout_game = (const float*)d_in[17];
    const float* Wm_played = (const float*)d_in[20];
    const float* bm_played = (const float*)d_in[21];
    const float* Wm_rev = (const float*)d_in[24];
    const float* bm_rev = (const float*)d_in[25];
    const int* ei_played_src = (const int*)d_in[26];
    const int* ei_played_dst = (const int*)d_in[27];
    const int* ei_rev_src = (const int*)d_in[28];
    const int* ei_rev_dst = (const int*)d_in[29];

    const int n_user = in_sizes[0] / DD;
    const int n_game = in_sizes[1] / DD;
    const int e_played = in_sizes[26];
    const int e_rev = in_sizes[28];

    float* out = (float*)d_out;
    float* out_user = out;                          // rows [0, n_user)
    float* out_game = out + (size_t)n_user * DD;    // rows [n_user, ..)

    // ---- workspace layout ----
    float* fws = (float*)d_ws;
    float* T0 = fws;                       // 64K f32
    float* T1 = T0 + DD * DD;              // 64K f32
    float* bb_played = T1 + DD * DD;       // 256
    float* bb_rev = bb_played + DD;        // 256
    short* Bsw_played = (short*)(bb_rev + DD);   // 64K bf16
    short* Bsw_rev = Bsw_played + DD * DD;       // 64K bf16
    int* iws = (int*)(Bsw_rev + DD * DD);
    int* off_game = iws;                      // n_game+1
    int* off_user = off_game + (n_game + 1);  // n_user+1
    int* cursor_game = off_user + (n_user + 1);
    int* cursor_user = cursor_game + n_game;
    int* sums_game = cursor_user + n_user;    // 256
    int* sums_user = sums_game + 256;         // 256
    int* perm_played = sums_user + 256;       // E
    int* perm_rev = perm_played + e_played;   // E
    (void)ws_size; (void)n_in; (void)out_size;

    // ---- zero histograms (off_game & off_user contiguous) ----
    hipMemsetAsync(off_game, 0, (size_t)(n_game + n_user + 2) * sizeof(int), stream);

    // ---- weight fusion ----
    gemm256x2<<<512, DD, 0, stream>>>(Wv_user, Wm_played, T0, Wv_game, Wm_rev, T1);
    gemm256_swz_x2<<<512, DD, 0, stream>>>(T0, Wout_game, Bsw_played,
                                           T1, Wout_user, Bsw_rev);
    bias_fuse2<<<2, DD, 0, stream>>>(bv_user, Wm_played, bm_played, Wout_game, bb_played,
                                     bv_game, Wm_rev, bm_rev, Wout_user, bb_rev);

    // ---- CSR build ----
    const int nch_g = (n_game + SCAN_CHUNK - 1) / SCAN_CHUNK;
    const int nch_u = (n_user + SCAN_CHUNK - 1) / SCAN_CHUNK;
    hist_kernel<<<(e_played + 255) / 256, 256, 0, stream>>>(ei_played_dst, off_game, e_played);
    hist_kernel<<<(e_rev + 255) / 256, 256, 0, stream>>>(ei_rev_dst, off_user, e_rev);
    scan_chunk<<<nch_g, 256, 0, stream>>>(off_game, sums_game, n_game);
    scan_chunk<<<nch_u, 256, 0, stream>>>(off_user, sums_user, n_user);
    scan_sums<<<1, 256, 0, stream>>>(sums_game, nch_g);
    scan_sums<<<1, 256, 0, stream>>>(sums_user, nch_u);
    scan_add<<<(n_game + 256) / 256, 256, 0, stream>>>(off_game, sums_game, n_game, e_played);
    scan_add<<<(n_user + 256) / 256, 256, 0, stream>>>(off_user, sums_user, n_user, e_rev);
    hipMemcpyAsync(cursor_game, off_game, (size_t)n_game * sizeof(int),
                   hipMemcpyDeviceToDevice, stream);
    hipMemcpyAsync(cursor_user, off_user, (size_t)n_user * sizeof(int),
                   hipMemcpyDeviceToDevice, stream);
    permute_kernel<<<(e_played + 255) / 256, 256, 0, stream>>>(
        ei_played_src, ei_played_dst, cursor_game, perm_played, e_played);
    permute_kernel<<<(e_rev + 255) / 256, 256, 0, stream>>>(
        ei_rev_src, ei_rev_dst, cursor_user, perm_rev, e_rev);

    // ---- fused aggregate + GEMM + epilogue ----
    agg_gemm<<<(n_user + 63) / 64, 256, 0, stream>>>(
        x_game, x_user, perm_rev, off_user, Bsw_rev, bb_rev, bout_user,
        out_user, n_user);
    agg_gemm<<<(n_game + 63) / 64, 256, 0, stream>>>(
        x_user, x_game, perm_played, off_game, Bsw_played, bb_played, bout_game,
        out_game, n_game);
}